// Round 13
// baseline (349.095 us; speedup 1.0000x reference)
//
#include <hip/hip_runtime.h>

typedef __attribute__((ext_vector_type(8))) short short8v;
typedef __attribute__((ext_vector_type(4))) float float4v;
typedef __attribute__((ext_vector_type(2))) unsigned int u32x2;
typedef __attribute__((ext_vector_type(4))) unsigned int u32x4;
typedef unsigned short u16;
typedef unsigned int u32;
typedef const __attribute__((address_space(1))) void* gas1;
typedef __attribute__((address_space(3))) void* las3;

#define NN 4096
#define EE 32768
#define DI 128
#define DO 128

__device__ __forceinline__ u16 f2bf(float f) {
    u32 u = __builtin_bit_cast(u32, f);
    u32 r = u + 0x7fffu + ((u >> 16) & 1u);   // round-to-nearest-even
    return (u16)(r >> 16);
}
__device__ __forceinline__ u32 pack2bf(float lo, float hi) {
    return (u32)f2bf(lo) | ((u32)f2bf(hi) << 16);
}
__device__ __forceinline__ void gload16(const void* g, void* l) {
    __builtin_amdgcn_global_load_lds((gas1)g, (las3)l, 16, 0, 0);
}
__device__ __forceinline__ u32 cvtpk(float lo, float hi) {
    u32 r;
    asm("v_cvt_pk_bf16_f32 %0, %1, %2" : "=v"(r) : "v"(lo), "v"(hi));
    return r;
}

// ---- helpers used by k1 only ----
template<int R, int C>
__device__ __forceinline__ void stage_f32_bf16(char* lds, const float* src, int ld) {
    constexpr int CH = C / 8;
    constexpr int ITER = (R * CH) / 256;
#pragma unroll
    for (int it = 0; it < ITER; ++it) {
        int c = it * 256 + (int)threadIdx.x;
        int row = c / CH, col8 = c % CH;
        const float* p = src + (size_t)row * ld + col8 * 8;
        float4v v0 = *(const float4v*)p;
        float4v v1 = *(const float4v*)(p + 4);
        u32x4 w;
        w[0] = pack2bf(v0[0], v0[1]);
        w[1] = pack2bf(v0[2], v0[3]);
        w[2] = pack2bf(v1[0], v1[1]);
        w[3] = pack2bf(v1[2], v1[3]);
        int kb = col8 * 16;
        *(u32x4*)(lds + row * (C * 2) + (kb ^ ((row & 7) << 4))) = w;
    }
}
template<int ROWB>
__device__ __forceinline__ short8v ldfrag(const char* base, int row16, int kk) {
    int l = (int)threadIdx.x & 63;
    int row = row16 + (l & 15);
    int kb = kk * 64 + ((l >> 4) << 4);
    return *(const short8v*)(base + row * ROWB + (kb ^ ((row & 7) << 4)));
}

// ---------- kernel 1: ATB[mo][n] = sum_i f_w[o][m*128+i] * x[n][i]  (mo = m*128+o) ----------
__global__ __launch_bounds__(256) void k1_ab(const float* __restrict__ x,
                                             const float* __restrict__ fw,
                                             u16* __restrict__ ATB) {
    __shared__ __align__(16) char lds[64 * 1024];
    char* aL = lds;              // [128 mo][128 i], ROWB 256
    char* bL = lds + 32 * 1024;  // [128 n][128 i]
    int mb = (int)blockIdx.x >> 5, nb = (int)blockIdx.x & 31;
    stage_f32_bf16<128, 128>(aL, fw + mb * 128, 2 * DI);
    stage_f32_bf16<128, 128>(bL, x + (size_t)nb * 128 * DI, DI);
    __syncthreads();
    int w = (int)threadIdx.x >> 6, l = (int)threadIdx.x & 63;
    int wr = w >> 1, wc = w & 1;
    float4v acc[4][4] = {};
#pragma unroll
    for (int kk = 0; kk < 4; ++kk) {
        short8v af[4], bf[4];
#pragma unroll
        for (int m = 0; m < 4; ++m) af[m] = ldfrag<256>(aL, wr * 64 + m * 16, kk);
#pragma unroll
        for (int n2 = 0; n2 < 4; ++n2) bf[n2] = ldfrag<256>(bL, wc * 64 + n2 * 16, kk);
#pragma unroll
        for (int m = 0; m < 4; ++m)
#pragma unroll
            for (int n2 = 0; n2 < 4; ++n2)
                acc[m][n2] = __builtin_amdgcn_mfma_f32_16x16x32_bf16(af[m], bf[n2], acc[m][n2], 0, 0, 0);
    }
#pragma unroll
    for (int m = 0; m < 4; ++m)
#pragma unroll
        for (int n2 = 0; n2 < 4; ++n2)
#pragma unroll
            for (int r = 0; r < 4; ++r) {
                int mo = mb * 128 + wr * 64 + m * 16 + ((l >> 4) << 2) + r;
                int n  = nb * 128 + wc * 64 + n2 * 16 + (l & 15);
                ATB[(size_t)mo * NN + n] = f2bf(acc[m][n2][r]);
            }
}

// ---------- kernel 2: YT[o][e] = relu(sum_mat sum_n ATB[mat][o][n]*M[n][e] + fb[o]) ----------
// R5 base, ONE change: A-frags load DIRECT global->reg one step ahead (L2-resident ATB,
// fragment layout == row-major) instead of gload_lds+ds_read. LDS 48->16KB, 3 blocks/CU.
// M path / barriers / epilogue byte-identical to R5.
__global__ __launch_bounds__(256, 3) void k2_y(const float* __restrict__ src,
                                               const float* __restrict__ tgt,
                                               const u16* __restrict__ ATB,
                                               const float* __restrict__ fb,
                                               u16* __restrict__ YT) {
    __shared__ __align__(16) char lds[16 * 1024]; // Mt bufs @0,8K: [64 e][64 n] bf16, XOR-swz
    const int eb = (int)blockIdx.x * 64;
    const int t = (int)threadIdx.x, w = t >> 6, l = t & 63;
    const int eq = t & 15, nq = t >> 4;           // 16 e-quads x 16 n-quads

    float4v r0, r1, r2, r3;
    auto loadT = [&](int ks) {                    // M[n0+nq*4 .. +3][eb+eq*4 .. +3] -> regs
        const float* M = (ks >= 64 ? tgt : src);
        const int n0 = (ks & 63) * 64;
        const float* p = M + (size_t)(n0 + nq * 4) * EE + eb + eq * 4;
        r0 = *(const float4v*)p;
        r1 = *(const float4v*)(p + EE);
        r2 = *(const float4v*)(p + 2 * EE);
        r3 = *(const float4v*)(p + 3 * EE);
    };
    // A-frags: row o = w*32 + m*16 + (l&15); 8 contiguous shorts at n0 + kk*32 + (l>>4)*8
    auto loadA = [&](int ks, short8v& A00, short8v& A01, short8v& A10, short8v& A11) {
        const int mat = ks >> 6, n0 = (ks & 63) * 64;
        const u16* base = ATB + (size_t)(mat * 128 + w * 32 + (l & 15)) * NN
                          + n0 + ((l >> 4) << 3);
        A00 = *(const short8v*)(base);                        // m=0, kk=0
        A01 = *(const short8v*)(base + 32);                   // m=0, kk=1
        A10 = *(const short8v*)(base + (size_t)16 * NN);      // m=1, kk=0
        A11 = *(const short8v*)(base + (size_t)16 * NN + 32); // m=1, kk=1
    };
    auto writeT = [&](int p) {                    // regs -> Mt [64 e][64 n] bf16, XOR-swz
        char* buf = lds + p * 8192;
#pragma unroll
        for (int j = 0; j < 4; ++j) {
            int e = eq * 4 + j;
            u32x2 w2;
            w2[0] = cvtpk(r0[j], r1[j]);
            w2[1] = cvtpk(r2[j], r3[j]);
            *(u32x2*)(buf + e * 128 + ((nq * 8) ^ ((e & 7) << 4))) = w2;
        }
    };

    short8v aA00, aA01, aA10, aA11, bA00, bA01, bA10, bA11; // 2 named A reg sets
    loadT(0);
    asm volatile("s_waitcnt vmcnt(0)" ::: "memory");   // prologue-only drain
    writeT(0);
    loadA(0, aA00, aA01, aA10, aA11);                  // A(0) for step 0
    __syncthreads();                                    // prologue only

    float4v acc[2][4] = {};
    // step ks: MFMA uses Acur=A(ks) (loaded last step) + Mt buf[ks&1];
    //          issues loadT(ks+1) + loadA(ks+1)->Anext; writeT(M(ks+1)) after vmcnt(4).
    auto step = [&](int ks,
                    short8v& c00, short8v& c01, short8v& c10, short8v& c11,
                    short8v& x00, short8v& x01, short8v& x10, short8v& x11) {
        const int nx = ks < 127 ? ks + 1 : 127;
        loadT(nx);                                 // 4 HBM reg loads (issued FIRST)
        loadA(nx, x00, x01, x10, x11);             // 4 L2 reg loads (next step's A)
        const char* bufB = lds + (ks & 1) * 8192;
        short8v bfr[2][4];
#pragma unroll
        for (int kk = 0; kk < 2; ++kk)
#pragma unroll
            for (int n2 = 0; n2 < 4; ++n2)
                bfr[kk][n2] = ldfrag<128>(bufB, n2 * 16, kk);
        // compiler inserts counted vmcnt for c** (loaded last step) + lgkm for bfr
#pragma unroll
        for (int n2 = 0; n2 < 4; ++n2) {
            acc[0][n2] = __builtin_amdgcn_mfma_f32_16x16x32_bf16(c00, bfr[0][n2], acc[0][n2], 0, 0, 0);
            acc[1][n2] = __builtin_amdgcn_mfma_f32_16x16x32_bf16(c10, bfr[0][n2], acc[1][n2], 0, 0, 0);
            acc[0][n2] = __builtin_amdgcn_mfma_f32_16x16x32_bf16(c01, bfr[1][n2], acc[0][n2], 0, 0, 0);
            acc[1][n2] = __builtin_amdgcn_mfma_f32_16x16x32_bf16(c11, bfr[1][n2], acc[1][n2], 0, 0, 0);
        }
        asm volatile("s_waitcnt vmcnt(4)" ::: "memory");   // loadT(ks+1) landed (loadA still out)
        __builtin_amdgcn_sched_barrier(0);
        writeT((ks + 1) & 1);
        asm volatile("s_waitcnt lgkmcnt(0)" ::: "memory"); // ds_writes visible
        __builtin_amdgcn_sched_barrier(0);
        __builtin_amdgcn_s_barrier();
    };

    for (int ks = 0; ks < 128; ks += 2) {
        step(ks,     aA00, aA01, aA10, aA11,  bA00, bA01, bA10, bA11);
        step(ks + 1, bA00, bA01, bA10, bA11,  aA00, aA01, aA10, aA11);
    }
#pragma unroll
    for (int m = 0; m < 2; ++m)
#pragma unroll
        for (int n2 = 0; n2 < 4; ++n2)
#pragma unroll
            for (int r = 0; r < 4; ++r) {
                const int o = w * 32 + m * 16 + ((l >> 4) << 2) + r;
                const int e = eb + n2 * 16 + (l & 15);
                float v = acc[m][n2][r] + fb[o];
                v = v > 0.f ? v : 0.f;
                YT[(size_t)o * EE + e] = f2bf(v);
            }
}

// ---------- kernel 3: part[kc][n][o] = sum_{e in chunk kc} tgt[n][e] * YT[o][e] ----------
// R5's proven k3, verbatim: grid 1024 = 64 mb x 16 kc. ALL staging via gload_lds
// (T as raw f32, cvtpk at frag read), counted vmcnt(8), never 0. 64KB LDS.
__global__ __launch_bounds__(256, 2) void k3_part(const float* __restrict__ tgt,
                                                  const u16* __restrict__ YT,
                                                  float* __restrict__ part) {
    __shared__ __align__(16) char lds[64 * 1024]; // T bufs @0,16K (f32); Y bufs @32K,48K (bf16)
    const int bid = (int)blockIdx.x;
    const int mb = bid & 63, kc = bid >> 6;
    const int e0 = kc * 2048;
    const int t = (int)threadIdx.x, w = t >> 6, l = t & 63;
    const int wr = w >> 1, wc = w & 1;

    auto stage = [&](int es, int p) {
        const int ec = e0 + es * 64;
#pragma unroll
        for (int q = 0; q < 4; ++q) {
            const int s = w * 4 + q;
            {   // T tile: f32 [64 n][64 e], rows 256B, chunk-swz x=r&7
                const int r = s * 4 + (l >> 4);
                const float* gp = tgt + (size_t)(mb * 64 + r) * EE + ec
                                  + (((l & 15) ^ (r & 7)) << 2);
                gload16(gp, lds + p * 16384 + s * 1024);
            }
            {   // Y tile: bf16 [128 o][64 e], rows 128B, chunk-swz x=r&7
                const int r = s * 8 + (l >> 3);
                const u16* gy = YT + (size_t)r * EE + ec + (((l & 7) ^ (r & 7)) << 3);
                gload16(gy, lds + 32768 + p * 16384 + s * 1024);
            }
        }
    };

    stage(0, 0);
    float4v acc[2][4] = {};
    for (int es = 0; es < 32; ++es) {
        stage(es < 31 ? es + 1 : 31, (es + 1) & 1);
        asm volatile("s_waitcnt vmcnt(8)" ::: "memory");
        __builtin_amdgcn_sched_barrier(0);
        __builtin_amdgcn_s_barrier();
        const char* bufT = lds + (es & 1) * 16384;
        const char* bufY = lds + 32768 + (es & 1) * 16384;
#pragma unroll
        for (int kk = 0; kk < 2; ++kk) {
            short8v af[2];
#pragma unroll
            for (int m = 0; m < 2; ++m) {
                const int row = wr * 32 + m * 16 + (l & 15);
                const int c0 = kk * 8 + ((l >> 4) << 1);
                float4v v0 = *(const float4v*)(bufT + row * 256 + ((c0 ^ (row & 7)) << 4));
                float4v v1 = *(const float4v*)(bufT + row * 256 + (((c0 + 1) ^ (row & 7)) << 4));
                u32x4 aw;
                aw[0] = cvtpk(v0[0], v0[1]);
                aw[1] = cvtpk(v0[2], v0[3]);
                aw[2] = cvtpk(v1[0], v1[1]);
                aw[3] = cvtpk(v1[2], v1[3]);
                af[m] = __builtin_bit_cast(short8v, aw);
            }
#pragma unroll
            for (int n2 = 0; n2 < 4; ++n2) {
                const int row = wc * 64 + n2 * 16 + (l & 15);
                short8v bf = *(const short8v*)(bufY + row * 128 +
                             ((kk * 64 + ((l >> 4) << 4)) ^ ((row & 7) << 4)));
#pragma unroll
                for (int m = 0; m < 2; ++m)
                    acc[m][n2] = __builtin_amdgcn_mfma_f32_16x16x32_bf16(
                        af[m], bf, acc[m][n2], 0, 0, 0);
            }
        }
        __builtin_amdgcn_sched_barrier(0);
        __builtin_amdgcn_s_barrier();
    }
#pragma unroll
    for (int m = 0; m < 2; ++m)
#pragma unroll
        for (int n2 = 0; n2 < 4; ++n2)
#pragma unroll
            for (int r = 0; r < 4; ++r) {
                const int n = mb * 64 + wr * 32 + m * 16 + ((l >> 4) << 2) + r;
                const int o = wc * 64 + n2 * 16 + (l & 15);
                part[((size_t)kc * NN + n) * DO + o] = acc[m][n2][r];
            }
}

// ---------- kernel 4: out = sum_kc part[kc] ----------
__global__ __launch_bounds__(256) void k4_red(const float* __restrict__ part,
                                              float* __restrict__ out) {
    size_t i = ((size_t)blockIdx.x * 256 + threadIdx.x) * 4;
    float4v s = {0.f, 0.f, 0.f, 0.f};
#pragma unroll
    for (int kc = 0; kc < 16; ++kc)
        s += *(const float4v*)(part + (size_t)kc * NN * DO + i);
    *(float4v*)(out + i) = s;
}

extern "C" void kernel_launch(void* const* d_in, const int* in_sizes, int n_in,
                              void* d_out, int out_size, void* d_ws, size_t ws_size,
                              hipStream_t stream) {
    const float* x   = (const float*)d_in[0];
    const float* src = (const float*)d_in[1];
    const float* tgt = (const float*)d_in[2];
    const float* fw  = (const float*)d_in[3];
    const float* fb  = (const float*)d_in[4];
    float* out = (float*)d_out;

    char* ws = (char*)d_ws;
    u16*   ATB  = (u16*)ws;                                  //  2 MB: [256][4096] bf16
    u16*   YT   = (u16*)(ws + (size_t)2 * 1024 * 1024);      //  8 MB: [128][32768] bf16
    float* PART = (float*)(ws + (size_t)16 * 1024 * 1024);   // 32 MB: [16][4096][128] f32

    k1_ab  <<<64,   256, 0, stream>>>(x, fw, ATB);
    k2_y   <<<512,  256, 0, stream>>>(src, tgt, ATB, fb, YT);
    k3_part<<<1024, 256, 0, stream>>>(tgt, YT, PART);
    k4_red <<<512,  256, 0, stream>>>(PART, out);
}

// Round 14
// 319.869 us; speedup vs baseline: 1.0914x; 1.0914x over previous
//
#include <hip/hip_runtime.h>

typedef __attribute__((ext_vector_type(8))) short short8v;
typedef __attribute__((ext_vector_type(4))) float float4v;
typedef __attribute__((ext_vector_type(2))) unsigned int u32x2;
typedef __attribute__((ext_vector_type(4))) unsigned int u32x4;
typedef unsigned short u16;
typedef unsigned int u32;
typedef const __attribute__((address_space(1))) void* gas1;
typedef __attribute__((address_space(3))) void* las3;

#define NN 4096
#define EE 32768
#define DI 128
#define DO 128

__device__ __forceinline__ u16 f2bf(float f) {
    u32 u = __builtin_bit_cast(u32, f);
    u32 r = u + 0x7fffu + ((u >> 16) & 1u);   // round-to-nearest-even
    return (u16)(r >> 16);
}
__device__ __forceinline__ u32 pack2bf(float lo, float hi) {
    return (u32)f2bf(lo) | ((u32)f2bf(hi) << 16);
}
__device__ __forceinline__ void gload16(const void* g, void* l) {
    __builtin_amdgcn_global_load_lds((gas1)g, (las3)l, 16, 0, 0);
}
__device__ __forceinline__ u32 cvtpk(float lo, float hi) {
    u32 r;
    asm("v_cvt_pk_bf16_f32 %0, %1, %2" : "=v"(r) : "v"(lo), "v"(hi));
    return r;
}

// ---- helpers used by k1 only ----
template<int R, int C>
__device__ __forceinline__ void stage_f32_bf16(char* lds, const float* src, int ld) {
    constexpr int CH = C / 8;
    constexpr int ITER = (R * CH) / 256;
#pragma unroll
    for (int it = 0; it < ITER; ++it) {
        int c = it * 256 + (int)threadIdx.x;
        int row = c / CH, col8 = c % CH;
        const float* p = src + (size_t)row * ld + col8 * 8;
        float4v v0 = *(const float4v*)p;
        float4v v1 = *(const float4v*)(p + 4);
        u32x4 w;
        w[0] = pack2bf(v0[0], v0[1]);
        w[1] = pack2bf(v0[2], v0[3]);
        w[2] = pack2bf(v1[0], v1[1]);
        w[3] = pack2bf(v1[2], v1[3]);
        int kb = col8 * 16;
        *(u32x4*)(lds + row * (C * 2) + (kb ^ ((row & 7) << 4))) = w;
    }
}
template<int ROWB>
__device__ __forceinline__ short8v ldfrag(const char* base, int row16, int kk) {
    int l = (int)threadIdx.x & 63;
    int row = row16 + (l & 15);
    int kb = kk * 64 + ((l >> 4) << 4);
    return *(const short8v*)(base + row * ROWB + (kb ^ ((row & 7) << 4)));
}

// ---------- kernel 1: ATB[mo][n] = sum_i f_w[o][m*128+i] * x[n][i]  (mo = m*128+o) ----------
__global__ __launch_bounds__(256) void k1_ab(const float* __restrict__ x,
                                             const float* __restrict__ fw,
                                             u16* __restrict__ ATB) {
    __shared__ __align__(16) char lds[64 * 1024];
    char* aL = lds;              // [128 mo][128 i], ROWB 256
    char* bL = lds + 32 * 1024;  // [128 n][128 i]
    int mb = (int)blockIdx.x >> 5, nb = (int)blockIdx.x & 31;
    stage_f32_bf16<128, 128>(aL, fw + mb * 128, 2 * DI);
    stage_f32_bf16<128, 128>(bL, x + (size_t)nb * 128 * DI, DI);
    __syncthreads();
    int w = (int)threadIdx.x >> 6, l = (int)threadIdx.x & 63;
    int wr = w >> 1, wc = w & 1;
    float4v acc[4][4] = {};
#pragma unroll
    for (int kk = 0; kk < 4; ++kk) {
        short8v af[4], bf[4];
#pragma unroll
        for (int m = 0; m < 4; ++m) af[m] = ldfrag<256>(aL, wr * 64 + m * 16, kk);
#pragma unroll
        for (int n2 = 0; n2 < 4; ++n2) bf[n2] = ldfrag<256>(bL, wc * 64 + n2 * 16, kk);
#pragma unroll
        for (int m = 0; m < 4; ++m)
#pragma unroll
            for (int n2 = 0; n2 < 4; ++n2)
                acc[m][n2] = __builtin_amdgcn_mfma_f32_16x16x32_bf16(af[m], bf[n2], acc[m][n2], 0, 0, 0);
    }
#pragma unroll
    for (int m = 0; m < 4; ++m)
#pragma unroll
        for (int n2 = 0; n2 < 4; ++n2)
#pragma unroll
            for (int r = 0; r < 4; ++r) {
                int mo = mb * 128 + wr * 64 + m * 16 + ((l >> 4) << 2) + r;
                int n  = nb * 128 + wc * 64 + n2 * 16 + (l & 15);
                ATB[(size_t)mo * NN + n] = f2bf(acc[m][n2][r]);
            }
}

// ---------- kernel 2: YT[o][e] = relu(sum_mat sum_n ATB[mat][o][n]*M[n][e] + fb[o]) ----------
// R5's proven structure, verbatim: grid 512 e-tiles of 64; 128 K-steps (64 src + 64 tgt).
// ATB: gload_lds dbuf (own-wave rows). M: global->reg->cvtpk->transposed bf16 LDS dbuf.
// Counted vmcnt(8)/(4), lgkmcnt(0) + ONE raw s_barrier per step — never vmcnt(0).
__global__ __launch_bounds__(256, 2) void k2_y(const float* __restrict__ src,
                                               const float* __restrict__ tgt,
                                               const u16* __restrict__ ATB,
                                               const float* __restrict__ fb,
                                               u16* __restrict__ YT) {
    __shared__ __align__(16) char lds[48 * 1024]; // ATB bufs @0,16K; Mt bufs @32K,40K
    const int eb = (int)blockIdx.x * 64;
    const int t = (int)threadIdx.x, w = t >> 6, l = t & 63;
    const int eq = t & 15, nq = t >> 4;           // 16 e-quads x 16 n-quads

    float4v r0, r1, r2, r3;
    auto loadT = [&](int ks) {                    // M[n0+nq*4 .. +3][eb+eq*4 .. +3] -> regs
        const float* M = (ks >= 64 ? tgt : src);
        const int n0 = (ks & 63) * 64;
        const float* p = M + (size_t)(n0 + nq * 4) * EE + eb + eq * 4;
        r0 = *(const float4v*)p;
        r1 = *(const float4v*)(p + EE);
        r2 = *(const float4v*)(p + 2 * EE);
        r3 = *(const float4v*)(p + 3 * EE);
    };
    auto gloadA = [&](int ks, int p) {            // ATB tile [128 o][64 n] bf16, pre-swz src
        const int mat = ks >> 6, n0 = (ks & 63) * 64;
        const u16* AB = ATB + (size_t)mat * 128 * NN + n0;
#pragma unroll
        for (int q = 0; q < 4; ++q) {
            const int s = w * 4 + q;
            const int r = s * 8 + (l >> 3);
            const u16* ga = AB + (size_t)r * NN + (((l & 7) ^ (r & 7)) << 3);
            gload16(ga, lds + p * 16384 + s * 1024);
        }
    };
    auto writeT = [&](int p) {                    // regs -> Mt [64 e][64 n] bf16, XOR-swz
        char* buf = lds + 32768 + p * 8192;
#pragma unroll
        for (int j = 0; j < 4; ++j) {
            int e = eq * 4 + j;
            u32x2 w2;
            w2[0] = cvtpk(r0[j], r1[j]);
            w2[1] = cvtpk(r2[j], r3[j]);
            *(u32x2*)(buf + e * 128 + ((nq * 8) ^ ((e & 7) << 4))) = w2;
        }
    };

    loadT(0);
    gloadA(0, 0);
    writeT(0);
    __syncthreads();   // prologue only (drains once; Mt(0)+ATB(0) visible)

    float4v acc[2][4] = {};
    for (int ks = 0; ks < 128; ++ks) {
        const int nx = ks < 127 ? ks + 1 : 127;   // last-step dup keeps vmcnt counts exact
        loadT(nx);                                 // 4 reg loads (issued FIRST)
        gloadA(nx, (ks + 1) & 1);                  // 4 gload_lds
        asm volatile("s_waitcnt vmcnt(8)" ::: "memory");   // ATB(ks) landed; 8 in flight
        __builtin_amdgcn_sched_barrier(0);
        const char* bufA = lds + (ks & 1) * 16384;
        const char* bufB = lds + 32768 + (ks & 1) * 8192;
        short8v af[2][2], bfr[2][4];
#pragma unroll
        for (int kk = 0; kk < 2; ++kk) {
#pragma unroll
            for (int m = 0; m < 2; ++m)
                af[kk][m] = ldfrag<128>(bufA, w * 32 + m * 16, kk);
#pragma unroll
            for (int n2 = 0; n2 < 4; ++n2)
                bfr[kk][n2] = ldfrag<128>(bufB, n2 * 16, kk);
        }
#pragma unroll
        for (int kk = 0; kk < 2; ++kk)
#pragma unroll
            for (int m = 0; m < 2; ++m)
#pragma unroll
                for (int n2 = 0; n2 < 4; ++n2)
                    acc[m][n2] = __builtin_amdgcn_mfma_f32_16x16x32_bf16(
                        af[kk][m], bfr[kk][n2], acc[m][n2], 0, 0, 0);
        asm volatile("s_waitcnt vmcnt(4)" ::: "memory");   // loadT(ks+1) regs ready
        __builtin_amdgcn_sched_barrier(0);
        writeT((ks + 1) & 1);
        asm volatile("s_waitcnt lgkmcnt(0)" ::: "memory"); // ds_writes visible
        __builtin_amdgcn_sched_barrier(0);
        __builtin_amdgcn_s_barrier();
    }
#pragma unroll
    for (int m = 0; m < 2; ++m)
#pragma unroll
        for (int n2 = 0; n2 < 4; ++n2)
#pragma unroll
            for (int r = 0; r < 4; ++r) {
                const int o = w * 32 + m * 16 + ((l >> 4) << 2) + r;
                const int e = eb + n2 * 16 + (l & 15);
                float v = acc[m][n2][r] + fb[o];
                v = v > 0.f ? v : 0.f;
                YT[(size_t)o * EE + e] = f2bf(v);
            }
}

// ---------- kernel 3: part[kc][n][o] = sum_{e in chunk kc} tgt[n][e] * YT[o][e] ----------
// R5's proven k3, verbatim: grid 1024 = 64 mb x 16 kc. ALL staging via gload_lds
// (T as raw f32, cvtpk at frag read), counted vmcnt(8), never 0. 64KB LDS.
__global__ __launch_bounds__(256, 2) void k3_part(const float* __restrict__ tgt,
                                                  const u16* __restrict__ YT,
                                                  float* __restrict__ part) {
    __shared__ __align__(16) char lds[64 * 1024]; // T bufs @0,16K (f32); Y bufs @32K,48K (bf16)
    const int bid = (int)blockIdx.x;
    const int mb = bid & 63, kc = bid >> 6;
    const int e0 = kc * 2048;
    const int t = (int)threadIdx.x, w = t >> 6, l = t & 63;
    const int wr = w >> 1, wc = w & 1;

    auto stage = [&](int es, int p) {
        const int ec = e0 + es * 64;
#pragma unroll
        for (int q = 0; q < 4; ++q) {
            const int s = w * 4 + q;
            {   // T tile: f32 [64 n][64 e], rows 256B, chunk-swz x=r&7
                const int r = s * 4 + (l >> 4);
                const float* gp = tgt + (size_t)(mb * 64 + r) * EE + ec
                                  + (((l & 15) ^ (r & 7)) << 2);
                gload16(gp, lds + p * 16384 + s * 1024);
            }
            {   // Y tile: bf16 [128 o][64 e], rows 128B, chunk-swz x=r&7
                const int r = s * 8 + (l >> 3);
                const u16* gy = YT + (size_t)r * EE + ec + (((l & 7) ^ (r & 7)) << 3);
                gload16(gy, lds + 32768 + p * 16384 + s * 1024);
            }
        }
    };

    stage(0, 0);
    float4v acc[2][4] = {};
    for (int es = 0; es < 32; ++es) {
        stage(es < 31 ? es + 1 : 31, (es + 1) & 1);
        asm volatile("s_waitcnt vmcnt(8)" ::: "memory");
        __builtin_amdgcn_sched_barrier(0);
        __builtin_amdgcn_s_barrier();
        const char* bufT = lds + (es & 1) * 16384;
        const char* bufY = lds + 32768 + (es & 1) * 16384;
#pragma unroll
        for (int kk = 0; kk < 2; ++kk) {
            short8v af[2];
#pragma unroll
            for (int m = 0; m < 2; ++m) {
                const int row = wr * 32 + m * 16 + (l & 15);
                const int c0 = kk * 8 + ((l >> 4) << 1);
                float4v v0 = *(const float4v*)(bufT + row * 256 + ((c0 ^ (row & 7)) << 4));
                float4v v1 = *(const float4v*)(bufT + row * 256 + (((c0 + 1) ^ (row & 7)) << 4));
                u32x4 aw;
                aw[0] = cvtpk(v0[0], v0[1]);
                aw[1] = cvtpk(v0[2], v0[3]);
                aw[2] = cvtpk(v1[0], v1[1]);
                aw[3] = cvtpk(v1[2], v1[3]);
                af[m] = __builtin_bit_cast(short8v, aw);
            }
#pragma unroll
            for (int n2 = 0; n2 < 4; ++n2) {
                const int row = wc * 64 + n2 * 16 + (l & 15);
                short8v bf = *(const short8v*)(bufY + row * 128 +
                             ((kk * 64 + ((l >> 4) << 4)) ^ ((row & 7) << 4)));
#pragma unroll
                for (int m = 0; m < 2; ++m)
                    acc[m][n2] = __builtin_amdgcn_mfma_f32_16x16x32_bf16(
                        af[m], bf, acc[m][n2], 0, 0, 0);
            }
        }
        __builtin_amdgcn_sched_barrier(0);
        __builtin_amdgcn_s_barrier();
    }
#pragma unroll
    for (int m = 0; m < 2; ++m)
#pragma unroll
        for (int n2 = 0; n2 < 4; ++n2)
#pragma unroll
            for (int r = 0; r < 4; ++r) {
                const int n = mb * 64 + wr * 32 + m * 16 + ((l >> 4) << 2) + r;
                const int o = wc * 64 + n2 * 16 + (l & 15);
                part[((size_t)kc * NN + n) * DO + o] = acc[m][n2][r];
            }
}

// ---------- kernel 4: out = sum_kc part[kc] ----------
__global__ __launch_bounds__(256) void k4_red(const float* __restrict__ part,
                                              float* __restrict__ out) {
    size_t i = ((size_t)blockIdx.x * 256 + threadIdx.x) * 4;
    float4v s = {0.f, 0.f, 0.f, 0.f};
#pragma unroll
    for (int kc = 0; kc < 16; ++kc)
        s += *(const float4v*)(part + (size_t)kc * NN * DO + i);
    *(float4v*)(out + i) = s;
}

extern "C" void kernel_launch(void* const* d_in, const int* in_sizes, int n_in,
                              void* d_out, int out_size, void* d_ws, size_t ws_size,
                              hipStream_t stream) {
    const float* x   = (const float*)d_in[0];
    const float* src = (const float*)d_in[1];
    const float* tgt = (const float*)d_in[2];
    const float* fw  = (const float*)d_in[3];
    const float* fb  = (const float*)d_in[4];
    float* out = (float*)d_out;

    char* ws = (char*)d_ws;
    u16*   ATB  = (u16*)ws;                                  //  2 MB: [256][4096] bf16
    u16*   YT   = (u16*)(ws + (size_t)2 * 1024 * 1024);      //  8 MB: [128][32768] bf16
    float* PART = (float*)(ws + (size_t)16 * 1024 * 1024);   // 32 MB: [16][4096][128] f32

    k1_ab  <<<64,   256, 0, stream>>>(x, fw, ATB);
    k2_y   <<<512,  256, 0, stream>>>(src, tgt, ATB, fb, YT);
    k3_part<<<1024, 256, 0, stream>>>(tgt, YT, PART);
    k4_red <<<512,  256, 0, stream>>>(PART, out);
}